// Round 1
// 511.475 us; speedup vs baseline: 1.1358x; 1.1358x over previous
//
#include <hip/hip_runtime.h>
#include <cstdint>

typedef __attribute__((ext_vector_type(8))) short short8;            // 8 bf16 = 4 VGPRs
typedef __attribute__((ext_vector_type(4))) float floatx4;           // MFMA C/D

__device__ __forceinline__ unsigned short f32_to_bf16_rne(float f) {
  uint32_t u = __float_as_uint(f);
  u += 0x7FFFu + ((u >> 16) & 1u);   // RNE (inputs finite normals)
  return (unsigned short)(u >> 16);
}

__device__ __forceinline__ ushort4 cvt4_f(float4 v) {
  ushort4 r;
  r.x = f32_to_bf16_rne(v.x); r.y = f32_to_bf16_rne(v.y);
  r.z = f32_to_bf16_rne(v.z); r.w = f32_to_bf16_rne(v.w);
  return r;
}
__device__ __forceinline__ ushort4 cvt4_i(int4 v) {
  ushort4 r;
  r.x = (unsigned short)(__float_as_uint((float)v.x) >> 16);
  r.y = (unsigned short)(__float_as_uint((float)v.y) >> 16);
  r.z = (unsigned short)(__float_as_uint((float)v.z) >> 16);
  r.w = (unsigned short)(__float_as_uint((float)v.w) >> 16);
  return r;
}

// Fused conversion (unchanged from verified kernel): x fp32->bf16, w int32->bf16 (exact).
__global__ void cvt_fused(const float4* __restrict__ x, const int4* __restrict__ w,
                          ushort4* __restrict__ ox, ushort4* __restrict__ ow, int nbx) {
  const int t = threadIdx.x;
  if ((int)blockIdx.x < nbx) {
    const int base = blockIdx.x * 512;
    float4 a = x[base + t];
    float4 b = x[base + 256 + t];
    ox[base + t]       = cvt4_f(a);
    ox[base + 256 + t] = cvt4_f(b);
  } else {
    const int base = ((int)blockIdx.x - nbx) * 512;
    int4 a = w[base + t];
    int4 b = w[base + 256 + t];
    ow[base + t]       = cvt4_i(a);
    ow[base + 256 + t] = cvt4_i(b);
  }
}

__device__ __forceinline__ void async16(const void* g, void* l) {
  __builtin_amdgcn_global_load_lds((__attribute__((address_space(1))) void*)(g),
                                   (__attribute__((address_space(3))) void*)(l), 16, 0, 0);
}

#define BARRIER() asm volatile("s_barrier" ::: "memory")

// 256x256 tile, BK=32, 4-deep LDS ring (128 KB), 8 waves (2x4), wave tile 128x64.
// Pipeline: stage K-tile kt+3 during kt; boundary wait = s_waitcnt vmcnt(8)
// (2 K-tiles in flight, never drained to 0 in the main loop).
// Swizzle: R2-verified involution seg^((row>>1)&3) — staging pre-swizzles the
// global source, LDS stays linear, reads apply the same XOR (conflict-free).
__global__ __launch_bounds__(512, 2) void gemm256_bt_bf16(
    const unsigned short* __restrict__ A, const unsigned short* __restrict__ B,
    const float* __restrict__ scale, const float* __restrict__ bias,
    float* __restrict__ C, int M, int N, int K) {
  constexpr int BM = 256, BN = 256, BK = 32;
  constexpr int ABK = BM * BK;            // 8192 ushorts: B half starts here
  constexpr int BUFSZ = (BM + BN) * BK;   // 16384 ushorts = 32 KB / buffer
  __shared__ __align__(16) unsigned short lds[4 * BUFSZ];  // 128 KB

  const int tid  = threadIdx.x;
  const int lane = tid & 63;
  const int wv   = tid >> 6;   // 8 waves
  const int wm   = wv >> 2;    // 0..1 -> 128 rows each
  const int wn   = wv & 3;     // 0..3 -> 64 cols each

  // T1: XCD-aware block swizzle (bijective; gridDim.x % 8 == 0 here)
  const int nwg = gridDim.x;
  const int bid = blockIdx.x;
  const int swz = ((nwg & 7) == 0) ? ((bid & 7) * (nwg >> 3) + (bid >> 3)) : bid;
  const int ntn = N / BN;
  const int tm = swz / ntn, tn = swz - tm * ntn;
  const int aM = tm * BM, bN = tn * BN;

  // staging: 256 rows x 4 segs(16B) per matrix = 1024 slots; thread t owns
  // slots t and t+512. physical slot p holds logical seg (p&3)^((row>>1)&3).
  const int t0 = tid, t1 = tid + 512;
  const int r0 = t0 >> 2, s0 = (t0 & 3) ^ ((r0 >> 1) & 3);
  const int r1 = t1 >> 2, s1 = (t1 & 3) ^ ((r1 >> 1) & 3);
  const unsigned short* gA0 = A + (size_t)(aM + r0) * K + s0 * 8;
  const unsigned short* gA1 = A + (size_t)(aM + r1) * K + s1 * 8;
  const unsigned short* gB0 = B + (size_t)(bN + r0) * K + s0 * 8;
  const unsigned short* gB1 = B + (size_t)(bN + r1) * K + s1 * 8;

  // frag reads: A[m=row16][k=quad*8+j], physical seg = quad ^ ((row>>1)&3)
  const int row16 = lane & 15;
  const int quad  = lane >> 4;
  const int seg   = (quad ^ ((row16 >> 1) & 3)) * 8;
  const int offA  = (wm * 128 + row16) * BK + seg;        // + i*16*BK
  const int offB  = ABK + (wn * 64 + row16) * BK + seg;   // + j*16*BK

  floatx4 acc[8][4] = {};

  const int NT = K / BK;
  // prologue: stage K-tiles 0..2 into ring slots 0..2 (12 loads/thread)
#pragma unroll
  for (int p = 0; p < 3; ++p) {
    unsigned short* d = lds + p * BUFSZ;
    const int ko = p * BK;
    async16(gA0 + ko, d + t0 * 8);
    async16(gA1 + ko, d + t1 * 8);
    async16(gB0 + ko, d + ABK + t0 * 8);
    async16(gB1 + ko, d + ABK + t1 * 8);
  }

  for (int kt = 0; kt < NT; ++kt) {
    const unsigned short* buf = lds + (kt & 3) * BUFSZ;
    unsigned short* dst = lds + ((kt + 3) & 3) * BUFSZ;   // == (kt-1)&3: freed last iter
    const int ko = (kt + 3) * BK;
    const bool pf = (kt + 3) < NT;

    // counted boundary wait: all of tile kt landed; tiles kt+1,kt+2 stay in flight
    if (kt < NT - 2)       asm volatile("s_waitcnt vmcnt(8)" ::: "memory");
    else if (kt == NT - 2) asm volatile("s_waitcnt vmcnt(4)" ::: "memory");
    else                   asm volatile("s_waitcnt vmcnt(0)" ::: "memory");
    BARRIER();  // all waves: tile kt visible, all reads of buffer (kt-1)&3 retired

    // ---- phase 0: B cols 0-3 (shared by both phases) + A rows 0-3
    short8 bf[4], af[4];
#pragma unroll
    for (int j = 0; j < 4; ++j) bf[j] = *(const short8*)(buf + offB + j * 16 * BK);
#pragma unroll
    for (int i = 0; i < 4; ++i) af[i] = *(const short8*)(buf + offA + i * 16 * BK);
    if (pf) {  // prefetch kt+3: A halves
      async16(gA0 + ko, dst + t0 * 8);
      async16(gA1 + ko, dst + t1 * 8);
    }
    BARRIER();
    __builtin_amdgcn_s_setprio(1);
#pragma unroll
    for (int i = 0; i < 4; ++i)
#pragma unroll
      for (int j = 0; j < 4; ++j)
        acc[i][j] = __builtin_amdgcn_mfma_f32_16x16x32_bf16(af[i], bf[j], acc[i][j], 0, 0, 0);
    __builtin_amdgcn_s_setprio(0);
    BARRIER();

    // ---- phase 1: A rows 4-7
    short8 ag[4];
#pragma unroll
    for (int i = 0; i < 4; ++i) ag[i] = *(const short8*)(buf + offA + (i + 4) * 16 * BK);
    if (pf) {  // prefetch kt+3: B halves
      async16(gB0 + ko, dst + ABK + t0 * 8);
      async16(gB1 + ko, dst + ABK + t1 * 8);
    }
    BARRIER();
    __builtin_amdgcn_s_setprio(1);
#pragma unroll
    for (int i = 0; i < 4; ++i)
#pragma unroll
      for (int j = 0; j < 4; ++j)
        acc[i + 4][j] = __builtin_amdgcn_mfma_f32_16x16x32_bf16(ag[i], bf[j], acc[i + 4][j], 0, 0, 0);
    __builtin_amdgcn_s_setprio(0);
    // no trailing barrier: next iteration's vmcnt+barrier is the boundary
  }

  // --- epilogue: C/D layout col=lane&15, row=(lane>>4)*4+reg (m89-verified)
#pragma unroll
  for (int j = 0; j < 4; ++j) {
    const int n = bN + wn * 64 + j * 16 + row16;
    const float s = scale[n];
    const float b = bias[n];
#pragma unroll
    for (int i = 0; i < 8; ++i) {
      const int m0 = aM + wm * 128 + i * 16 + quad * 4;
      floatx4 c = acc[i][j];
      C[(size_t)(m0 + 0) * N + n] = c[0] * s + b;
      C[(size_t)(m0 + 1) * N + n] = c[1] * s + b;
      C[(size_t)(m0 + 2) * N + n] = c[2] * s + b;
      C[(size_t)(m0 + 3) * N + n] = c[3] * s + b;
    }
  }
}

// Insurance only: used if shapes/ws don't fit the fast path.
__global__ void naive_kernel(const float* __restrict__ x, const int* __restrict__ w,
                             const float* __restrict__ s, const float* __restrict__ b,
                             float* __restrict__ y, int M, int N, int K) {
  int n = blockIdx.x * blockDim.x + threadIdx.x;
  int m = blockIdx.y;
  if (n >= N) return;
  float acc = 0.f;
  for (int k = 0; k < K; ++k) acc += x[(size_t)m * K + k] * (float)w[(size_t)n * K + k];
  y[(size_t)m * N + n] = acc * s[n] + b[n];
}

extern "C" void kernel_launch(void* const* d_in, const int* in_sizes, int n_in,
                              void* d_out, int out_size, void* d_ws, size_t ws_size,
                              hipStream_t stream) {
  const float* x     = (const float*)d_in[0];
  const int*   wq    = (const int*)d_in[1];
  const float* scale = (const float*)d_in[2];
  const float* bias  = (const float*)d_in[3];
  float* y = (float*)d_out;

  const int xN = in_sizes[0];           // M*K
  const int wN = in_sizes[1];           // N*K
  const int N  = in_sizes[2];           // D_OUT
  const int K  = wN / N;
  const int M  = xN / K;

  const size_t need = (size_t)xN * 2 + (size_t)wN * 2;  // 96 MiB here
  if (ws_size >= need && (M % 256) == 0 && (N % 256) == 0 && (K % 32) == 0 &&
      K >= 128 && (xN % 2048) == 0 && (wN % 2048) == 0) {
    unsigned short* xb = (unsigned short*)d_ws;
    unsigned short* wb = xb + (size_t)xN;
    const int nbx = xN / 2048, nbw = wN / 2048;
    cvt_fused<<<nbx + nbw, 256, 0, stream>>>((const float4*)x, (const int4*)wq,
                                             (ushort4*)xb, (ushort4*)wb, nbx);
    const int nwg = (M / 256) * (N / 256);
    gemm256_bt_bf16<<<nwg, 512, 0, stream>>>(xb, wb, scale, bias, y, M, N, K);
  } else {
    dim3 grid((N + 255) / 256, M);
    naive_kernel<<<grid, 256, 0, stream>>>(x, wq, scale, bias, y, M, N, K);
  }
}